// Round 3
// baseline (108.068 us; speedup 1.0000x reference)
//
#include <hip/hip_runtime.h>
#include <hip/hip_bf16.h>

// Problem constants
#define B_N   8192
#define OBS   128
#define HID   512
#define HEADS 4
#define VSZ   256
#define NU    64
#define TOPK  8
#define NOPT  16
#define KEXT  160   // GEMM K extended: 128 x-cols + 1 bias col + 31 zero pad

typedef __bf16 bf16_t;
typedef __bf16 bf16x4 __attribute__((ext_vector_type(4)));
typedef __bf16 bf16x8 __attribute__((ext_vector_type(8)));
typedef float  f32x4  __attribute__((ext_vector_type(4)));

// Workspace layout (bytes)
#define OFF_WEFF 0u         // 512*256*4 = 524288
#define OFF_A    524288u    // 16*4
#define OFF_DP   524352u    // 256*4
#define OFF_MT   525376u    // 256*160*2 = 81920 (bf16 M^T, row v: k 0..127 = M,
                            //  k=128 -> c, k 129..159 = 0), 16B aligned

// ---------------------------------------------------------------------------
// Kernel 1: blocks 0..511: weff[j][v] = 0.25 * sum_head value_w[j][h*256+v]
//           block 512:     A[opt] (top-8 sigmoid sum / 64) and Dp[v]=0.125*be[v]
__global__ void k_pre(const float* __restrict__ vw, const float* __restrict__ p_w,
                      const float* __restrict__ p_b, const float* __restrict__ vb,
                      float* __restrict__ weff, float* __restrict__ A,
                      float* __restrict__ Dp) {
    if (blockIdx.x < HID) {
        int j = blockIdx.x, v = threadIdx.x;
        const float* r = vw + j * (HEADS * VSZ);
        weff[j * VSZ + v] = 0.25f * (r[v] + r[v + VSZ] + r[v + 2 * VSZ] + r[v + 3 * VSZ]);
        return;
    }
    // A + Dp block. 4 waves; wave w handles options 4w..4w+3.
    int tid  = threadIdx.x;
    int lane = tid & 63;
    int w    = tid >> 6;
    #pragma unroll
    for (int oo = 0; oo < 4; ++oo) {
        int o = w * 4 + oo;
        float cur = p_w[o * NU + lane] + p_b[lane];
        float sum = 0.f;
        #pragma unroll
        for (int t = 0; t < TOPK; ++t) {
            float m = cur;
            #pragma unroll
            for (int off = 32; off >= 1; off >>= 1)
                m = fmaxf(m, __shfl_xor(m, off));
            sum += 1.f / (1.f + expf(-m));
            unsigned long long bal = __ballot(cur == m);
            int first = __ffsll(bal) - 1;      // lowest index: jax tie-break
            if (lane == first) cur = -1e30f;
        }
        if (lane == 0) A[o] = sum * (1.f / NU);
    }
    if (tid < VSZ)
        Dp[tid] = 0.125f * 0.25f * (vb[tid] + vb[tid + VSZ] + vb[tid + 2 * VSZ] + vb[tid + 3 * VSZ]);
}

// ---------------------------------------------------------------------------
// Kernel 2: M^T (bf16, row stride KEXT).
// Blocks 0..31: 4 k-rows each (k = blockIdx*4 .. +3), 1024 threads =
//   4 j-quarters x 256 v. Each weff load feeds 4 FMAs (4x reuse vs r2).
// Block 32: c row (k=128) via pre_fc_b, then zero-fill k 129..159.
__global__ void k_mt(const float* __restrict__ pw, const float* __restrict__ pb,
                     const float* __restrict__ weff, bf16_t* __restrict__ mt) {
    int v  = threadIdx.x & 255;
    int jq = threadIdx.x >> 8;                 // 0..3
    __shared__ float red[4][4][VSZ];           // [jq][t][v], 16 KB
    const float* wf = weff + (jq * 128) * VSZ + v;

    if (blockIdx.x < 32) {
        int k0 = blockIdx.x * 4;
        const float* w0 = pw + (k0 + 0) * HID + jq * 128;
        const float* w1 = pw + (k0 + 1) * HID + jq * 128;
        const float* w2 = pw + (k0 + 2) * HID + jq * 128;
        const float* w3 = pw + (k0 + 3) * HID + jq * 128;
        float a0 = 0.f, a1 = 0.f, a2 = 0.f, a3 = 0.f;
        #pragma unroll 8
        for (int j = 0; j < 128; ++j) {
            float wv = wf[j * VSZ];
            a0 += w0[j] * wv;
            a1 += w1[j] * wv;
            a2 += w2[j] * wv;
            a3 += w3[j] * wv;
        }
        red[jq][0][v] = a0; red[jq][1][v] = a1;
        red[jq][2][v] = a2; red[jq][3][v] = a3;
        __syncthreads();
        if (jq == 0) {
            bf16x4 o;
            #pragma unroll
            for (int t = 0; t < 4; ++t)
                o[t] = (bf16_t)(red[0][t][v] + red[1][t][v] + red[2][t][v] + red[3][t][v]);
            *(bf16x4*)(mt + v * KEXT + k0) = o;   // 8B aligned: v*320 + k0*2
        }
        return;
    }
    // c row + zero pad
    const float* wr = pb + jq * 128;
    float a0 = 0.f;
    #pragma unroll 8
    for (int j = 0; j < 128; ++j) a0 += wr[j] * wf[j * VSZ];
    red[jq][0][v] = a0;
    __syncthreads();
    if (jq == 0) {
        float s = red[0][0][v] + red[1][0][v] + red[2][0][v] + red[3][0][v];
        bf16_t* row = mt + v * KEXT;
        row[128] = (bf16_t)s;
        #pragma unroll
        for (int k = 129; k < KEXT; ++k) row[k] = (bf16_t)0.f;
    }
}

// ---------------------------------------------------------------------------
// Kernel 3: out[b][v] = A[opt[b]] * (x' @ M')[b][v] + Dp[v]
// x' = [x | 1 | 0...], M' = [M ; c ; 0...]; K = 160. f32 x -> bf16 in-register.
// MFMA 16x16x32. Block = 4 waves; wave: 16 rows x 64 cols.
// grid (8192/64, 256/64) = (128, 4) = 512 blocks -> 2 blocks/CU.
__launch_bounds__(256)
__global__ void k_main(const float* __restrict__ x, const bf16_t* __restrict__ mt,
                       const int* __restrict__ opt, const float* __restrict__ A,
                       const float* __restrict__ Dp, float* __restrict__ out) {
    int wave = threadIdx.x >> 6;
    int lane = threadIdx.x & 63;
    int mrow = lane & 15;
    int quad = lane >> 4;
    int r0   = blockIdx.x * 64 + wave * 16;
    int c0   = blockIdx.y * 64;

    f32x4 acc[4];
    #pragma unroll
    for (int t = 0; t < 4; ++t) acc[t] = (f32x4){0.f, 0.f, 0.f, 0.f};

    const float*  xr = x + (r0 + mrow) * OBS + quad * 8;
    const bf16_t* mb = mt + (c0 + mrow) * KEXT + quad * 8;

    #pragma unroll
    for (int kt = 0; kt < 5; ++kt) {
        bf16x8 a;
        if (kt < 4) {
            f32x4 lo = *(const f32x4*)(xr + kt * 32);
            f32x4 hi = *(const f32x4*)(xr + kt * 32 + 4);
            a[0] = (bf16_t)lo[0]; a[1] = (bf16_t)lo[1];
            a[2] = (bf16_t)lo[2]; a[3] = (bf16_t)lo[3];
            a[4] = (bf16_t)hi[0]; a[5] = (bf16_t)hi[1];
            a[6] = (bf16_t)hi[2]; a[7] = (bf16_t)hi[3];
        } else {
            #pragma unroll
            for (int j = 0; j < 8; ++j) a[j] = (bf16_t)0.f;
            if (quad == 0) a[0] = (bf16_t)1.0f;   // k=128: the bias column
        }
        #pragma unroll
        for (int t = 0; t < 4; ++t) {
            bf16x8 b = *(const bf16x8*)(mb + t * 16 * KEXT + kt * 32);
            acc[t] = __builtin_amdgcn_mfma_f32_16x16x32_bf16(a, b, acc[t], 0, 0, 0);
        }
    }

    // C/D layout: col=lane&15, row=quad*4+reg
    #pragma unroll
    for (int r = 0; r < 4; ++r) {
        int row = r0 + quad * 4 + r;
        float av = A[opt[row]];
        float* orow = out + row * VSZ;
        #pragma unroll
        for (int t = 0; t < 4; ++t) {
            int col = c0 + t * 16 + mrow;
            orow[col] = av * acc[t][r] + Dp[col];
        }
    }
}

// ---------------------------------------------------------------------------
extern "C" void kernel_launch(void* const* d_in, const int* in_sizes, int n_in,
                              void* d_out, int out_size, void* d_ws, size_t ws_size,
                              hipStream_t stream) {
    const float* x        = (const float*)d_in[0];
    const int*   option   = (const int*)  d_in[1];
    const float* pre_fc_w = (const float*)d_in[2];
    const float* pre_fc_b = (const float*)d_in[3];
    const float* value_w  = (const float*)d_in[4];
    const float* value_b  = (const float*)d_in[5];
    const float* p_w      = (const float*)d_in[6];
    const float* p_b      = (const float*)d_in[7];
    float* out = (float*)d_out;

    char* ws = (char*)d_ws;
    float*  weff = (float*) (ws + OFF_WEFF);
    float*  A    = (float*) (ws + OFF_A);
    float*  Dp   = (float*) (ws + OFF_DP);
    bf16_t* mt   = (bf16_t*)(ws + OFF_MT);

    k_pre <<<dim3(HID + 1), dim3(VSZ), 0, stream>>>(value_w, p_w, p_b, value_b, weff, A, Dp);
    k_mt  <<<dim3(33), dim3(1024), 0, stream>>>(pre_fc_w, pre_fc_b, weff, mt);
    k_main<<<dim3(B_N / 64, VSZ / 64), dim3(256), 0, stream>>>(x, mt, option, A, Dp, out);
}